// Round 3
// baseline (423.898 us; speedup 1.0000x reference)
//
#include <hip/hip_runtime.h>
#include <hip/hip_bf16.h>
#include <math.h>

// CASSBlock fused: LN -> dir-select -> [gather -> fc1 -> dwconv3 -> gelu -> fc2] -> +x
// B=32 H=W=64 C=192 DIN=384 L=4096.
// Round 3: occupancy attack. fc1 A-frags straight from global (no sX tile) -> LDS 35KB
// -> 4 blocks/CU. Fast tanh-GELU. ln_kernel reworked to 32-lane groups.
//
// ws layout (bytes):
//   xn   bf16 [32*4096*192]   @ 0          (50,331,648)
//   g    f32  [32*4096]       @ 50331648   (524,288)
//   w1s  bf16 [73728]         @ 50855936   (fragment-ordered fc1_w)
//   w2s  bf16 [73728]         @ 51003392   (fragment-ordered fc2_w)
//   dir  int  [32]            @ 51150848

typedef __bf16 bf16x8 __attribute__((ext_vector_type(8)));
typedef float f32x4 __attribute__((ext_vector_type(4)));
typedef __hip_bfloat16 hb;

#define XN_OFF   0
#define G_OFF    50331648
#define W1S_OFF  50855936
#define W2S_OFF  51003392
#define DIR_OFF  51150848

__device__ __forceinline__ float fast_gelu(float v) {
  // tanh-form gelu; max |diff vs exact erf-gelu| ~3e-3, negligible after fc2
  float u = v * (0.7978845608f + 0.0356774081f * v * v);
  float a = fabsf(u);
  float e = __expf(-2.f * a);
  float t = (1.f - e) * __builtin_amdgcn_rcpf(1.f + e);
  t = copysignf(t, u);
  return 0.5f * v * (1.f + t);
}

// ---------------- Kernel 1: LayerNorm + channel-mean g ----------------
// 32-lane groups: one pixel per group, 6 channels per lane. 8 pixels per block.
__global__ __launch_bounds__(256) void ln_kernel(
    const float* __restrict__ x, const float* __restrict__ nw,
    const float* __restrict__ nb, hb* __restrict__ xn, float* __restrict__ g) {
  int t = threadIdx.x;
  int lane = t & 31;
  long pix = ((long)blockIdx.x << 3) + (t >> 5);
  const float* xp = x + pix * 192 + lane * 6;
  float2 va = *(const float2*)(xp);
  float2 vb = *(const float2*)(xp + 2);
  float2 vc = *(const float2*)(xp + 4);
  float s1 = va.x + va.y + vb.x + vb.y + vc.x + vc.y;
  float s2 = va.x * va.x + va.y * va.y + vb.x * vb.x + vb.y * vb.y +
             vc.x * vc.x + vc.y * vc.y;
  #pragma unroll
  for (int off = 16; off; off >>= 1) {
    s1 += __shfl_xor(s1, off);
    s2 += __shfl_xor(s2, off);
  }
  float mu = s1 * (1.f / 192.f);
  float var = s2 * (1.f / 192.f) - mu * mu;
  float rstd = rsqrtf(var + 1e-5f);
  int c = lane * 6;
  float y[6];
  float vv[6] = {va.x, va.y, vb.x, vb.y, vc.x, vc.y};
  float gs = 0.f;
  #pragma unroll
  for (int i = 0; i < 6; i++) {
    y[i] = (vv[i] - mu) * rstd * nw[c + i] + nb[c + i];
    gs += y[i];
  }
  #pragma unroll
  for (int off = 16; off; off >>= 1) gs += __shfl_xor(gs, off);
  unsigned short us[6];
  #pragma unroll
  for (int i = 0; i < 6; i++) {
    hb h = __float2bfloat16(y[i]);
    us[i] = reinterpret_cast<unsigned short&>(h);
  }
  hb* xo = xn + pix * 192 + c;
  ((ushort2*)xo)[0] = make_ushort2(us[0], us[1]);
  ((ushort2*)xo)[1] = make_ushort2(us[2], us[3]);
  ((ushort2*)xo)[2] = make_ushort2(us[4], us[5]);
  if (lane == 0) g[pix] = gs * (1.f / 192.f);
}

// ---------------- Kernel 2: direction selector ----------------
__global__ __launch_bounds__(256) void sel_kernel(
    const float* __restrict__ g, const float* __restrict__ w1,
    const float* __restrict__ b1, const float* __restrict__ w2,
    const float* __restrict__ b2, int* __restrict__ dir) {
  __shared__ float gt[64][65];
  __shared__ float red[8];
  int b = blockIdx.x, t = threadIdx.x;
  const float* gb = g + (long)b * 4096;
  for (int i = t; i < 4096; i += 256) gt[i >> 6][i & 63] = gb[i];
  __syncthreads();
  float ah = 0.f, av = 0.f;
  for (int i = t; i < 3968; i += 256) {
    int r = i / 62, j = i - r * 62 + 1;
    float d = fabsf(gt[r][j + 1] - gt[r][j - 1]);
    if (r == 1 || r == 62) d *= 2.f;
    ah += d;
  }
  for (int i = t; i < 3968; i += 256) {
    int r = (i >> 6) + 1, c = i & 63;
    float d = fabsf(gt[r + 1][c] - gt[r - 1][c]);
    if (c == 1 || c == 62) d *= 2.f;
    av += d;
  }
  #pragma unroll
  for (int off = 32; off; off >>= 1) {
    ah += __shfl_xor(ah, off);
    av += __shfl_xor(av, off);
  }
  if ((t & 63) == 0) { red[(t >> 6) * 2] = ah; red[(t >> 6) * 2 + 1] = av; }
  __syncthreads();
  if (t == 0) {
    float sh = 0.f, sv = 0.f;
    for (int w = 0; w < 4; w++) { sh += red[w * 2]; sv += red[w * 2 + 1]; }
    sh *= (1.f / 4224.f);
    sv *= (1.f / 4224.f);
    float sc[4] = {sh, sv, 0.5f * (sh + sv), fabsf(sh - sv)};
    float hid[16];
    #pragma unroll
    for (int i = 0; i < 16; i++) {
      float a = b1[i];
      for (int k = 0; k < 4; k++) a += sc[k] * w1[i * 4 + k];
      hid[i] = fmaxf(a, 0.f);
    }
    float best = -1e30f; int bi = 0;
    for (int j = 0; j < 4; j++) {
      float a = b2[j];
      for (int i = 0; i < 16; i++) a += hid[i] * w2[j * 16 + i];
      if (a > best) { best = a; bi = j; }
    }
    dir[b] = bi;
  }
}

// ---------------- Kernel 3: weight shuffle to MFMA fragment order ----------------
// frag f = nt*KS + ks; element j, lane: W[n=nt*16+(lane&15)][k=ks*32+(lane>>4)*8+j]
__global__ __launch_bounds__(256) void wshuf_kernel(
    const float* __restrict__ fc1_w, const float* __restrict__ fc2_w,
    hb* __restrict__ w1s, hb* __restrict__ w2s) {
  int idx = blockIdx.x * 256 + threadIdx.x;
  const float* w; hb* o; int K, KS, li;
  if (idx < 73728) { w = fc1_w; o = w1s; K = 192; KS = 6;  li = idx; }
  else             { w = fc2_w; o = w2s; K = 384; KS = 12; li = idx - 73728; }
  int j = li & 7, lane = (li >> 3) & 63, f = li >> 9;
  int ks = f % KS, nt = f / KS;
  int n = nt * 16 + (lane & 15);
  int k = ks * 32 + ((lane >> 4) << 3) + j;
  o[li] = __float2bfloat16(w[n * K + k]);
}

// ---------------- Kernel 4: fused seq block ----------------
// block = (mt, b): 64 output rows. fc1 A-frags direct from global; h tile (66 rows,
// half-width per pass) in LDS; conv+gelu in regs; fc2 acc persists across passes.
#define SH_STRIDE 196
__global__ __launch_bounds__(256, 4) void fused_kernel(
    const hb* __restrict__ xn, const hb* __restrict__ w1s, const hb* __restrict__ w2s,
    const float* __restrict__ fc1_b, const float* __restrict__ fc2_b,
    const float* __restrict__ conv_w, const float* __restrict__ conv_b,
    const float* __restrict__ x, const int* __restrict__ dirp,
    float* __restrict__ out) {
  __shared__ hb sH[66 * SH_STRIDE];    // 25,872 B
  __shared__ float4 cvt[384];          // 6,144 B  {w0,w1,w2,b}
  __shared__ float sB1[384];           // 1,536 B
  __shared__ float sB2[192];           //   768 B   => ~34.3 KB total

  int b = blockIdx.y, mt = blockIdx.x;
  int dir = dirp[b];
  int l0 = mt << 6;
  int t = threadIdx.x;

  for (int d = t; d < 384; d += 256) {
    cvt[d] = make_float4(conv_w[d * 3], conv_w[d * 3 + 1], conv_w[d * 3 + 2], conv_b[d]);
    sB1[d] = fc1_b[d];
  }
  if (t < 192) sB2[t] = fc2_b[t];
  __syncthreads();

  int wave = t >> 6, lane = t & 63;
  int m16 = lane & 15, q = lane >> 4;
  const bf16x8* b1base = (const bf16x8*)w1s;
  const bf16x8* b2base = (const bf16x8*)w2s;
  const hb* xnb = xn + (long)b * 4096 * 192;

  f32x4 acc2[12];
  #pragma unroll
  for (int i = 0; i < 12; i++) acc2[i] = (f32x4){0.f, 0.f, 0.f, 0.f};

  int m_local = wave * 16 + m16;
  bool hm_ok = (mt > 0) || (m_local > 0);
  bool hp_ok = (mt < 63) || (m_local < 63);

  for (int pass = 0; pass < 2; pass++) {
    // ---- fc1 half: n in [pass*192, +192). 5 M-tiles x 12 nt = 60 units / 4 waves
    int u0 = wave * 15;
    int tile = u0 / 12, ntl = u0 - tile * 12;
    int cur_tile = -1;
    bf16x8 af[6];
    for (int u = 0; u < 15; u++) {
      if (tile != cur_tile) {
        cur_tile = tile;
        int rs = tile * 16 + m16;
        if (rs > 65) rs = 65;                 // clamp into staged halo range
        int l = l0 - 1 + rs;
        int lc = min(max(l, 0), 4095);        // seq-edge clamp (masked at conv)
        int src;
        if (dir == 0)      src = lc;
        else if (dir == 3) src = ((lc & 63) << 6) + 63 - (lc >> 6);
        else               src = ((lc & 63) << 6) + (lc >> 6);
        const bf16x8* ap = (const bf16x8*)(xnb + (long)src * 192) + q;
        #pragma unroll
        for (int ks = 0; ks < 6; ks++) af[ks] = ap[ks * 4];
      }
      int nt = pass * 12 + ntl;
      f32x4 acc = {0.f, 0.f, 0.f, 0.f};
      #pragma unroll
      for (int ks = 0; ks < 6; ks++)
        acc = __builtin_amdgcn_mfma_f32_16x16x32_bf16(af[ks], b1base[(nt * 6 + ks) * 64 + lane], acc, 0, 0, 0);
      float bias = sB1[nt * 16 + m16];
      int n_local = ntl * 16 + m16;
      #pragma unroll
      for (int r = 0; r < 4; r++) {
        int grow = tile * 16 + q * 4 + r;
        if (grow < 66) sH[grow * SH_STRIDE + n_local] = __float2bfloat16(acc[r] + bias);
      }
      ntl++;
      if (ntl == 12) { ntl = 0; tile++; }
    }
    __syncthreads();

    // ---- conv + gelu into A-frags (regs), fc2 accumulate
    bf16x8 af2[6];
    const hb* hrow = sH + m_local * SH_STRIDE + q * 8;
    #pragma unroll
    for (int ksl = 0; ksl < 6; ksl++) {
      bf16x8 vm = *(const bf16x8*)(hrow + ksl * 32);
      bf16x8 vc = *(const bf16x8*)(hrow + SH_STRIDE + ksl * 32);
      bf16x8 vp = *(const bf16x8*)(hrow + 2 * SH_STRIDE + ksl * 32);
      int d0 = pass * 192 + ksl * 32 + q * 8;
      bf16x8 o;
      #pragma unroll
      for (int j = 0; j < 8; j++) {
        float4 cw = cvt[d0 + j];
        float hm = hm_ok ? (float)vm[j] : 0.f;
        float hc = (float)vc[j];
        float hp = hp_ok ? (float)vp[j] : 0.f;
        float v = hm * cw.x + hc * cw.y + hp * cw.z + cw.w;
        o[j] = (__bf16)fast_gelu(v);
      }
      af2[ksl] = o;
    }
    #pragma unroll
    for (int nt = 0; nt < 12; nt++) {
      #pragma unroll
      for (int ksl = 0; ksl < 6; ksl++) {
        int ksg = pass * 6 + ksl;
        acc2[nt] = __builtin_amdgcn_mfma_f32_16x16x32_bf16(af2[ksl], b2base[(nt * 12 + ksg) * 64 + lane], acc2[nt], 0, 0, 0);
      }
    }
    if (pass == 0) __syncthreads();  // before fc1 of pass 1 overwrites sH
  }

  // ---- epilogue: out = x + acc2 + fc2_b
  long obase = ((long)b * 4096 + l0 + wave * 16 + q * 4) * 192;
  #pragma unroll
  for (int nt = 0; nt < 12; nt++) {
    int c = nt * 16 + m16;
    float bias = sB2[c];
    #pragma unroll
    for (int r = 0; r < 4; r++) {
      long idx = obase + (long)r * 192 + c;
      out[idx] = x[idx] + acc2[nt][r] + bias;
    }
  }
}

extern "C" void kernel_launch(void* const* d_in, const int* in_sizes, int n_in,
                              void* d_out, int out_size, void* d_ws, size_t ws_size,
                              hipStream_t stream) {
  const float* x      = (const float*)d_in[0];
  const float* norm_w = (const float*)d_in[1];
  const float* norm_b = (const float*)d_in[2];
  const float* sel_w1 = (const float*)d_in[3];
  const float* sel_b1 = (const float*)d_in[4];
  const float* sel_w2 = (const float*)d_in[5];
  const float* sel_b2 = (const float*)d_in[6];
  const float* fc1_w  = (const float*)d_in[7];
  const float* fc1_b  = (const float*)d_in[8];
  const float* conv_w = (const float*)d_in[9];
  const float* conv_b = (const float*)d_in[10];
  const float* fc2_w  = (const float*)d_in[11];
  const float* fc2_b  = (const float*)d_in[12];
  float* out = (float*)d_out;
  char* ws = (char*)d_ws;

  hb* xn    = (hb*)(ws + XN_OFF);
  float* g  = (float*)(ws + G_OFF);
  hb* w1s   = (hb*)(ws + W1S_OFF);
  hb* w2s   = (hb*)(ws + W2S_OFF);
  int* dir  = (int*)(ws + DIR_OFF);

  ln_kernel<<<16384, 256, 0, stream>>>(x, norm_w, norm_b, xn, g);
  sel_kernel<<<32, 256, 0, stream>>>(g, sel_w1, sel_b1, sel_w2, sel_b2, dir);
  wshuf_kernel<<<576, 256, 0, stream>>>(fc1_w, fc2_w, w1s, w2s);
  dim3 gg(64, 32);
  fused_kernel<<<gg, 256, 0, stream>>>(xn, w1s, w2s, fc1_b, fc2_b,
                                       conv_w, conv_b, x, dir, out);
}

// Round 4
// 357.813 us; speedup vs baseline: 1.1847x; 1.1847x over previous
//
#include <hip/hip_runtime.h>
#include <hip/hip_bf16.h>
#include <math.h>

// CASSBlock fused: LN -> dir-select -> [gather -> fc1 -> dwconv3 -> gelu -> fc2] -> +x
// B=32 H=W=64 C=192 DIN=384 L=4096.
// Round 4: regular unrollable structure. 32-row h-tiles (30 outputs + 2 halo).
// fc1: wave = n-quarter x BOTH 16-row M-tiles (B reused 2x, loops fully unrolled).
// fc2: wave = (M-tile, n-half), K streamed, acc only 24 regs. One barrier between.
//
// ws layout (bytes):
//   xn   bf16 [32*4096*192]   @ 0          (50,331,648)
//   g    f32  [32*4096]       @ 50331648   (524,288)
//   w1s  bf16 [73728]         @ 50855936   (fragment-ordered fc1_w)
//   w2s  bf16 [73728]         @ 51003392   (fragment-ordered fc2_w)
//   dir  int  [32]            @ 51150848

typedef __bf16 bf16x8 __attribute__((ext_vector_type(8)));
typedef float f32x4 __attribute__((ext_vector_type(4)));
typedef __hip_bfloat16 hb;

#define XN_OFF   0
#define G_OFF    50331648
#define W1S_OFF  50855936
#define W2S_OFF  51003392
#define DIR_OFF  51150848

__device__ __forceinline__ float fast_gelu(float v) {
  float u = v * (0.7978845608f + 0.0356774081f * v * v);
  float a = fabsf(u);
  float e = __expf(-2.f * a);
  float tt = (1.f - e) * __builtin_amdgcn_rcpf(1.f + e);
  tt = copysignf(tt, u);
  return 0.5f * v * (1.f + tt);
}

__device__ __forceinline__ unsigned short bf16bits(float f) {
  hb h = __float2bfloat16(f);
  return *reinterpret_cast<unsigned short*>(&h);
}

// ---------------- Kernel 1: LayerNorm + channel-mean g (two-stage LDS) ----------------
// 16 pixels/block. Coalesced float4 loads; 16-lane-group reduction; coalesced stores.
__global__ __launch_bounds__(256) void ln_kernel(
    const float* __restrict__ x, const float* __restrict__ nw,
    const float* __restrict__ nb, hb* __restrict__ xn, float* __restrict__ g) {
  __shared__ float4 xt[768];          // 16 px * 48 f4 = 12288 B
  __shared__ unsigned int ytu[1536];  // 16 px * 96 dw (bf16 pairs) = 6144 B
  __shared__ float snw[192], snb[192];
  int t = threadIdx.x;
  long pixbase = (long)blockIdx.x * 16;
  const float4* x4 = (const float4*)(x + pixbase * 192);
  #pragma unroll
  for (int i = 0; i < 3; i++) xt[t + i * 256] = x4[t + i * 256];
  if (t < 192) { snw[t] = nw[t]; snb[t] = nb[t]; }
  __syncthreads();

  int p = t >> 4, sub = t & 15;
  const float4* row = xt + p * 48 + sub * 3;
  float4 f0 = row[0], f1 = row[1], f2 = row[2];
  float v[12] = {f0.x, f0.y, f0.z, f0.w, f1.x, f1.y, f1.z, f1.w,
                 f2.x, f2.y, f2.z, f2.w};
  float s1 = 0.f, s2 = 0.f;
  #pragma unroll
  for (int i = 0; i < 12; i++) { s1 += v[i]; s2 += v[i] * v[i]; }
  #pragma unroll
  for (int off = 8; off; off >>= 1) {
    s1 += __shfl_xor(s1, off);
    s2 += __shfl_xor(s2, off);
  }
  float mu = s1 * (1.f / 192.f);
  float var = s2 * (1.f / 192.f) - mu * mu;
  float rstd = rsqrtf(var + 1e-5f);
  int c0 = sub * 12;
  float ys[12], gs = 0.f;
  #pragma unroll
  for (int i = 0; i < 12; i++) {
    ys[i] = (v[i] - mu) * rstd * snw[c0 + i] + snb[c0 + i];
    gs += ys[i];
  }
  #pragma unroll
  for (int off = 8; off; off >>= 1) gs += __shfl_xor(gs, off);
  if (sub == 0) g[pixbase + p] = gs * (1.f / 192.f);
  unsigned int* yo = ytu + p * 96 + sub * 6;
  #pragma unroll
  for (int i = 0; i < 6; i++)
    yo[i] = (unsigned int)bf16bits(ys[2 * i]) |
            ((unsigned int)bf16bits(ys[2 * i + 1]) << 16);
  __syncthreads();
  const float4* yt4 = (const float4*)ytu;
  float4* o4 = (float4*)(xn + pixbase * 192);
  o4[t] = yt4[t];
  if (t < 128) o4[t + 256] = yt4[t + 256];
}

// ---------------- Kernel 2: direction selector ----------------
__global__ __launch_bounds__(256) void sel_kernel(
    const float* __restrict__ g, const float* __restrict__ w1,
    const float* __restrict__ b1, const float* __restrict__ w2,
    const float* __restrict__ b2, int* __restrict__ dir) {
  __shared__ float gt[64][65];
  __shared__ float red[8];
  int b = blockIdx.x, t = threadIdx.x;
  const float* gb = g + (long)b * 4096;
  for (int i = t; i < 4096; i += 256) gt[i >> 6][i & 63] = gb[i];
  __syncthreads();
  float ah = 0.f, av = 0.f;
  for (int i = t; i < 3968; i += 256) {
    int r = i / 62, j = i - r * 62 + 1;
    float d = fabsf(gt[r][j + 1] - gt[r][j - 1]);
    if (r == 1 || r == 62) d *= 2.f;
    ah += d;
  }
  for (int i = t; i < 3968; i += 256) {
    int r = (i >> 6) + 1, c = i & 63;
    float d = fabsf(gt[r + 1][c] - gt[r - 1][c]);
    if (c == 1 || c == 62) d *= 2.f;
    av += d;
  }
  #pragma unroll
  for (int off = 32; off; off >>= 1) {
    ah += __shfl_xor(ah, off);
    av += __shfl_xor(av, off);
  }
  if ((t & 63) == 0) { red[(t >> 6) * 2] = ah; red[(t >> 6) * 2 + 1] = av; }
  __syncthreads();
  if (t == 0) {
    float sh = 0.f, sv = 0.f;
    for (int w = 0; w < 4; w++) { sh += red[w * 2]; sv += red[w * 2 + 1]; }
    sh *= (1.f / 4224.f);
    sv *= (1.f / 4224.f);
    float sc[4] = {sh, sv, 0.5f * (sh + sv), fabsf(sh - sv)};
    float hid[16];
    #pragma unroll
    for (int i = 0; i < 16; i++) {
      float a = b1[i];
      for (int k = 0; k < 4; k++) a += sc[k] * w1[i * 4 + k];
      hid[i] = fmaxf(a, 0.f);
    }
    float best = -1e30f; int bi = 0;
    for (int j = 0; j < 4; j++) {
      float a = b2[j];
      for (int i = 0; i < 16; i++) a += hid[i] * w2[j * 16 + i];
      if (a > best) { best = a; bi = j; }
    }
    dir[b] = bi;
  }
}

// ---------------- Kernel 3: weight shuffle to MFMA fragment order ----------------
__global__ __launch_bounds__(256) void wshuf_kernel(
    const float* __restrict__ fc1_w, const float* __restrict__ fc2_w,
    hb* __restrict__ w1s, hb* __restrict__ w2s) {
  int idx = blockIdx.x * 256 + threadIdx.x;
  const float* w; hb* o; int K, KS, li;
  if (idx < 73728) { w = fc1_w; o = w1s; K = 192; KS = 6;  li = idx; }
  else             { w = fc2_w; o = w2s; K = 384; KS = 12; li = idx - 73728; }
  int j = li & 7, lane = (li >> 3) & 63, f = li >> 9;
  int ks = f % KS, nt = f / KS;
  int n = nt * 16 + (lane & 15);
  int k = ks * 32 + ((lane >> 4) << 3) + j;
  o[li] = __float2bfloat16(w[n * K + k]);
}

// ---------------- Kernel 4: fused seq block ----------------
// block = (mt, b): h rows l0-1 .. l0+30 (32 rows), outputs l0 .. l0+29.
#define SH_STR 196
__global__ __launch_bounds__(256, 4) void fused_kernel(
    const hb* __restrict__ xn, const hb* __restrict__ w1s, const hb* __restrict__ w2s,
    const float* __restrict__ fc1_b, const float* __restrict__ fc2_b,
    const float* __restrict__ conv_w, const float* __restrict__ conv_b,
    const float* __restrict__ x, const int* __restrict__ dirp,
    float* __restrict__ out) {
  __shared__ hb sH[2][32 * SH_STR];   // 25,088 B
  __shared__ float4 cvt[384];         //  6,144 B
  __shared__ float sB1[384];          //  1,536 B
  __shared__ float sB2[192];          //    768 B  => ~33.5 KB

  int b = blockIdx.y, mt = blockIdx.x;
  int dir = dirp[b];
  int l0 = mt * 30;
  int t = threadIdx.x;

  for (int d = t; d < 384; d += 256) {
    cvt[d] = make_float4(conv_w[d * 3], conv_w[d * 3 + 1], conv_w[d * 3 + 2], conv_b[d]);
    sB1[d] = fc1_b[d];
  }
  if (t < 192) sB2[t] = fc2_b[t];

  int wave = t >> 6, lane = t & 63;
  int m16 = lane & 15, q = lane >> 4;
  const hb* xnb = xn + (long)b * 4096 * 192;

  // ---- fc1 A-frags: both 16-row tiles, rows tl*16+m16 (h-row), k full 192
  bf16x8 af[2][6];
  #pragma unroll
  for (int tl = 0; tl < 2; tl++) {
    int hr = tl * 16 + m16;
    int l = l0 - 1 + hr;
    int lc = min(max(l, 0), 4095);
    int src;
    if (dir == 0)      src = lc;
    else if (dir == 3) src = ((lc & 63) << 6) + 63 - (lc >> 6);
    else               src = ((lc & 63) << 6) + (lc >> 6);
    const bf16x8* ap = (const bf16x8*)(xnb + (long)src * 192) + q;
    #pragma unroll
    for (int ks = 0; ks < 6; ks++) af[tl][ks] = ap[ks * 4];
  }
  __syncthreads();  // sB1/cvt/sB2 staged

  // ---- fc1: wave w handles nt = 6w..6w+5 for both tiles; B loaded once, used 2x
  {
    int buf = wave >> 1;
    int ntbase = wave * 6;
    #pragma unroll
    for (int i = 0; i < 6; i++) {
      int nt = ntbase + i;
      const bf16x8* bp = (const bf16x8*)w1s + (long)(nt * 6) * 64 + lane;
      f32x4 c0 = {0.f, 0.f, 0.f, 0.f}, c1 = {0.f, 0.f, 0.f, 0.f};
      #pragma unroll
      for (int ks = 0; ks < 6; ks++) {
        bf16x8 bf = bp[ks * 64];
        c0 = __builtin_amdgcn_mfma_f32_16x16x32_bf16(af[0][ks], bf, c0, 0, 0, 0);
        c1 = __builtin_amdgcn_mfma_f32_16x16x32_bf16(af[1][ks], bf, c1, 0, 0, 0);
      }
      float bias = sB1[nt * 16 + m16];
      int ncol = (nt - buf * 12) * 16 + m16;
      hb* s = &sH[buf][0];
      #pragma unroll
      for (int r = 0; r < 4; r++) {
        s[(q * 4 + r) * SH_STR + ncol]      = __float2bfloat16(c0[r] + bias);
        s[(16 + q * 4 + r) * SH_STR + ncol] = __float2bfloat16(c1[r] + bias);
      }
    }
  }
  __syncthreads();

  // ---- conv + gelu into fc2 A-frags; fc2 K=384 streamed; wave = (tile2, n-half)
  int tile2 = wave & 1, nth = wave >> 1;
  int hr = tile2 * 16 + m16;
  int l_c = l0 - 1 + hr;
  bool hm_ok = (l_c >= 1);
  bool hp_ok = (l_c <= 4094);
  int rm = hr > 0 ? hr - 1 : 0;
  int rp = hr < 31 ? hr + 1 : 31;
  bf16x8 af2[12];
  #pragma unroll
  for (int ks = 0; ks < 12; ks++) {
    int bb = ks / 6, kl = ks - bb * 6;
    int col = kl * 32 + q * 8;
    const hb* base = &sH[bb][0];
    bf16x8 vm = *(const bf16x8*)(base + rm * SH_STR + col);
    bf16x8 vc = *(const bf16x8*)(base + hr * SH_STR + col);
    bf16x8 vp = *(const bf16x8*)(base + rp * SH_STR + col);
    int d0 = ks * 32 + q * 8;
    bf16x8 o;
    #pragma unroll
    for (int j = 0; j < 8; j++) {
      float4 cw = cvt[d0 + j];
      float hm = hm_ok ? (float)vm[j] : 0.f;
      float hc = (float)vc[j];
      float hp = hp_ok ? (float)vp[j] : 0.f;
      o[j] = (__bf16)fast_gelu(hm * cw.x + hc * cw.y + hp * cw.z + cw.w);
    }
    af2[ks] = o;
  }
  f32x4 acc[6];
  #pragma unroll
  for (int i = 0; i < 6; i++) acc[i] = (f32x4){0.f, 0.f, 0.f, 0.f};
  #pragma unroll
  for (int i2 = 0; i2 < 6; i2++) {
    int nt2 = nth * 6 + i2;
    const bf16x8* bp = (const bf16x8*)w2s + (long)(nt2 * 12) * 64 + lane;
    #pragma unroll
    for (int ks = 0; ks < 12; ks++)
      acc[i2] = __builtin_amdgcn_mfma_f32_16x16x32_bf16(af2[ks], bp[ks * 64], acc[i2], 0, 0, 0);
  }

  // ---- epilogue: out = x + acc + fc2_b for valid rows (hr_r in [1,30], l <= 4095)
  #pragma unroll
  for (int i2 = 0; i2 < 6; i2++) {
    int c = (nth * 6 + i2) * 16 + m16;
    float bias = sB2[c];
    #pragma unroll
    for (int r = 0; r < 4; r++) {
      int hr_r = tile2 * 16 + q * 4 + r;
      int l_r = l0 - 1 + hr_r;
      if (hr_r >= 1 && hr_r <= 30 && l_r <= 4095) {
        long idx = ((long)b * 4096 + l_r) * 192 + c;
        out[idx] = x[idx] + acc[i2][r] + bias;
      }
    }
  }
}

extern "C" void kernel_launch(void* const* d_in, const int* in_sizes, int n_in,
                              void* d_out, int out_size, void* d_ws, size_t ws_size,
                              hipStream_t stream) {
  const float* x      = (const float*)d_in[0];
  const float* norm_w = (const float*)d_in[1];
  const float* norm_b = (const float*)d_in[2];
  const float* sel_w1 = (const float*)d_in[3];
  const float* sel_b1 = (const float*)d_in[4];
  const float* sel_w2 = (const float*)d_in[5];
  const float* sel_b2 = (const float*)d_in[6];
  const float* fc1_w  = (const float*)d_in[7];
  const float* fc1_b  = (const float*)d_in[8];
  const float* conv_w = (const float*)d_in[9];
  const float* conv_b = (const float*)d_in[10];
  const float* fc2_w  = (const float*)d_in[11];
  const float* fc2_b  = (const float*)d_in[12];
  float* out = (float*)d_out;
  char* ws = (char*)d_ws;

  hb* xn    = (hb*)(ws + XN_OFF);
  float* g  = (float*)(ws + G_OFF);
  hb* w1s   = (hb*)(ws + W1S_OFF);
  hb* w2s   = (hb*)(ws + W2S_OFF);
  int* dir  = (int*)(ws + DIR_OFF);

  wshuf_kernel<<<576, 256, 0, stream>>>(fc1_w, fc2_w, w1s, w2s);
  ln_kernel<<<8192, 256, 0, stream>>>(x, norm_w, norm_b, xn, g);
  sel_kernel<<<32, 256, 0, stream>>>(g, sel_w1, sel_b1, sel_w2, sel_b2, dir);
  dim3 gg(137, 32);
  fused_kernel<<<gg, 256, 0, stream>>>(xn, w1s, w2s, fc1_b, fc2_b,
                                       conv_w, conv_b, x, dir, out);
}